// Round 2
// baseline (1362.804 us; speedup 1.0000x reference)
//
#include <hip/hip_runtime.h>
#include <hip/hip_bf16.h>

#define D 50
#define GLAM 0.05555555555555555f   // gamma * lambda = (1/(2*0.9)) * 0.1

// ---- degree init: self-loop weight = 1.0 on both in/out degrees ----
__global__ void k_init_deg(float* __restrict__ odeg, float* __restrict__ ideg, int n) {
    int i = blockIdx.x * blockDim.x + threadIdx.x;
    if (i < n) { odeg[i] = 1.0f; ideg[i] = 1.0f; }
}

// ---- weighted degree accumulation over edges ----
__global__ void k_deg(const float* __restrict__ ew, const int* __restrict__ src,
                      const int* __restrict__ dst, float* __restrict__ odeg,
                      float* __restrict__ ideg, int e) {
    int i = blockIdx.x * blockDim.x + threadIdx.x;
    if (i < e) {
        float w = ew[i];
        atomicAdd(&odeg[src[i]], w);
        atomicAdd(&ideg[dst[i]], w);
    }
}

// ---- deg -> 1/sqrt(deg), in place (deg >= 1 always, from self loop) ----
__global__ void k_rsqrt(float* __restrict__ odeg, float* __restrict__ ideg, int n) {
    int i = blockIdx.x * blockDim.x + threadIdx.x;
    if (i < n) { odeg[i] = rsqrtf(odeg[i]); ideg[i] = rsqrtf(ideg[i]); }
}

// ---- per-edge normalized weight ----
__global__ void k_w(const float* __restrict__ ew, const int* __restrict__ src,
                    const int* __restrict__ dst, const float* __restrict__ iso,
                    const float* __restrict__ isi, float* __restrict__ w, int e) {
    int i = blockIdx.x * blockDim.x + threadIdx.x;
    if (i < e) w[i] = ew[i] * iso[src[i]] * isi[dst[i]];
}

// ---- x0 = feat (fp32 copy into workspace) ----
__global__ void k_copyx(const float* __restrict__ feat, float* __restrict__ x, int nd) {
    int i = blockIdx.x * blockDim.x + threadIdx.x;
    if (i < nd) x[i] = feat[i];
}

// ---- agg init with self-loop contribution: agg[i] = iso[i]*isi[i]*x[i] ----
__global__ void k_init_agg(const float* __restrict__ x, const float* __restrict__ iso,
                           const float* __restrict__ isi, float* __restrict__ agg, int nd) {
    int idx = blockIdx.x * blockDim.x + threadIdx.x;
    if (idx < nd) {
        int i = idx / D;
        agg[idx] = iso[i] * isi[i] * x[idx];
    }
}

// ---- edge scatter: one 64-lane wave per edge, lanes 0..49 carry features ----
__global__ void k_spmm(const int* __restrict__ src, const int* __restrict__ dst,
                       const float* __restrict__ w, const float* __restrict__ x,
                       float* __restrict__ agg, int e) {
    int lane = threadIdx.x & 63;
    int eidx = blockIdx.x * (blockDim.x >> 6) + (threadIdx.x >> 6);
    if (eidx >= e) return;
    int s = src[eidx];
    int t = dst[eidx];
    float we = w[eidx];
    if (lane < D) {
        atomicAdd(&agg[t * D + lane], we * x[s * D + lane]);
    }
}

// ---- prox: x_new = feat + shrink(agg - feat); one wave per node ----
__global__ void k_prox(const float* __restrict__ agg, const float* __restrict__ feat,
                       float* __restrict__ xout, int n) {
    int lane = threadIdx.x & 63;
    int node = blockIdx.x * (blockDim.x >> 6) + (threadIdx.x >> 6);
    if (node >= n) return;
    float d = 0.0f, f = 0.0f;
    if (lane < D) {
        float a = agg[node * D + lane];
        f = feat[node * D + lane];
        d = a - f;
    }
    float s = d * d;
    #pragma unroll
    for (int m = 1; m < 64; m <<= 1) s += __shfl_xor(s, m, 64);
    float norm = sqrtf(s);
    float scale = 0.0f;
    if (norm > 0.0f) scale = fmaxf(norm - GLAM, 0.0f) / norm;
    if (lane < D) {
        xout[node * D + lane] = f + scale * d;
    }
}

extern "C" void kernel_launch(void* const* d_in, const int* in_sizes, int n_in,
                              void* d_out, int out_size, void* d_ws, size_t ws_size,
                              hipStream_t stream) {
    const float* feat = (const float*)d_in[0];
    const float* ew   = (const float*)d_in[1];
    const int* src = (const int*)d_in[2];
    const int* dst = (const int*)d_in[3];

    const int nd = in_sizes[0];      // N * D
    const int n  = nd / D;           // N nodes
    const int e  = in_sizes[1];      // E edges

    float* x    = (float*)d_ws;      // current iterate [nd]
    float* agg  = x + nd;            // SpMM accumulator [nd]
    float* odeg = agg + nd;          // becomes inv_sqrt_out [n]
    float* ideg = odeg + n;          // becomes inv_sqrt_in [n]
    float* w    = ideg + n;          // normalized edge weights [e]

    float* out  = (float*)d_out;

    const int B = 256;

    k_init_deg<<<(n + B - 1) / B, B, 0, stream>>>(odeg, ideg, n);
    k_deg<<<(e + B - 1) / B, B, 0, stream>>>(ew, src, dst, odeg, ideg, e);
    k_rsqrt<<<(n + B - 1) / B, B, 0, stream>>>(odeg, ideg, n);
    k_w<<<(e + B - 1) / B, B, 0, stream>>>(ew, src, dst, odeg, ideg, w, e);
    k_copyx<<<(nd + B - 1) / B, B, 0, stream>>>(feat, x, nd);

    const int wavesPerBlock = B / 64;           // 4
    const int spmmGrid = (e + wavesPerBlock - 1) / wavesPerBlock;
    const int proxGrid = (n + wavesPerBlock - 1) / wavesPerBlock;

    for (int k = 0; k < 3; ++k) {
        k_init_agg<<<(nd + B - 1) / B, B, 0, stream>>>(x, odeg, ideg, agg, nd);
        k_spmm<<<spmmGrid, B, 0, stream>>>(src, dst, w, x, agg, e);
        float* xo = (k == 2) ? out : x;
        k_prox<<<proxGrid, B, 0, stream>>>(agg, feat, xo, n);
    }
}

// Round 3
// 767.422 us; speedup vs baseline: 1.7758x; 1.7758x over previous
//
#include <hip/hip_runtime.h>
#include <hip/hip_bf16.h>

#define D 50
#define GLAM 0.05555555555555555f   // gamma * lambda = (1/(2*0.9)) * 0.1
#define SCAN_B 1024

// ---- init: degrees to 1.0 (self loop), counts to 0 ----
__global__ void k_init(float* __restrict__ odeg, float* __restrict__ ideg,
                       int* __restrict__ cnt, int n) {
    int i = blockIdx.x * blockDim.x + threadIdx.x;
    if (i < n) { odeg[i] = 1.0f; ideg[i] = 1.0f; cnt[i] = 0; }
}

// ---- weighted degrees + dst histogram in one pass ----
__global__ void k_deg_hist(const float* __restrict__ ew, const int* __restrict__ src,
                           const int* __restrict__ dst, float* __restrict__ odeg,
                           float* __restrict__ ideg, int* __restrict__ cnt, int e) {
    int i = blockIdx.x * blockDim.x + threadIdx.x;
    if (i < e) {
        float w = ew[i];
        int s = src[i], t = dst[i];
        atomicAdd(&odeg[s], w);
        atomicAdd(&ideg[t], w);
        atomicAdd(&cnt[t], 1);
    }
}

__global__ void k_rsqrt(float* __restrict__ odeg, float* __restrict__ ideg, int n) {
    int i = blockIdx.x * blockDim.x + threadIdx.x;
    if (i < n) { odeg[i] = rsqrtf(odeg[i]); ideg[i] = rsqrtf(ideg[i]); }
}

// ---- exclusive scan of cnt -> rowptr (3-kernel standard scan) ----
__global__ void k_scan1(const int* __restrict__ cnt, int* __restrict__ rowptr,
                        int* __restrict__ bsum, int n) {
    __shared__ int s[SCAN_B];
    int i = blockIdx.x * SCAN_B + threadIdx.x;
    int v = (i < n) ? cnt[i] : 0;
    s[threadIdx.x] = v; __syncthreads();
    for (int off = 1; off < SCAN_B; off <<= 1) {
        int t = (threadIdx.x >= (unsigned)off) ? s[threadIdx.x - off] : 0;
        __syncthreads();
        s[threadIdx.x] += t; __syncthreads();
    }
    if (i < n) rowptr[i] = s[threadIdx.x] - v;          // exclusive
    if (threadIdx.x == SCAN_B - 1) bsum[blockIdx.x] = s[threadIdx.x];
}

__global__ void k_scan2(int* __restrict__ bsum, int nb) {
    __shared__ int s[SCAN_B];
    int v = (threadIdx.x < (unsigned)nb) ? bsum[threadIdx.x] : 0;
    s[threadIdx.x] = v; __syncthreads();
    for (int off = 1; off < SCAN_B; off <<= 1) {
        int t = (threadIdx.x >= (unsigned)off) ? s[threadIdx.x - off] : 0;
        __syncthreads();
        s[threadIdx.x] += t; __syncthreads();
    }
    if (threadIdx.x < (unsigned)nb) bsum[threadIdx.x] = s[threadIdx.x] - v;  // exclusive
}

__global__ void k_scan3(int* __restrict__ rowptr, int* __restrict__ cursor,
                        const int* __restrict__ bsum, int n) {
    int i = blockIdx.x * SCAN_B + threadIdx.x;
    if (i < n) {
        int r = rowptr[i] + bsum[blockIdx.x];
        rowptr[i] = r;
        cursor[i] = r;
    }
}

// ---- scatter edges into dst-CSR with normalized weight ----
__global__ void k_scatter(const float* __restrict__ ew, const int* __restrict__ src,
                          const int* __restrict__ dst, const float* __restrict__ iso,
                          const float* __restrict__ isi, int* __restrict__ cursor,
                          int* __restrict__ col, float* __restrict__ wv, int e) {
    int i = blockIdx.x * blockDim.x + threadIdx.x;
    if (i < e) {
        int s = src[i], t = dst[i];
        int pos = atomicAdd(&cursor[t], 1);
        col[pos] = s;
        wv[pos]  = ew[i] * iso[s] * isi[t];
    }
}

// ---- fused iteration: self-loop + CSR gather + prox, one wave per node ----
__global__ void k_iter(const int* __restrict__ rowptr, const int* __restrict__ rowend,
                       const int* __restrict__ col, const float* __restrict__ wv,
                       const float* __restrict__ xin, const float* __restrict__ feat,
                       const float* __restrict__ iso, const float* __restrict__ isi,
                       float* __restrict__ xout, int n) {
    int lane = threadIdx.x & 63;
    int node = blockIdx.x * (blockDim.x >> 6) + (threadIdx.x >> 6);
    if (node >= n) return;

    float selfw = iso[node] * isi[node];
    float f = 0.0f, acc = 0.0f;
    if (lane < D) {
        f = feat[node * D + lane];
        acc = selfw * xin[node * D + lane];
    }

    int beg = rowptr[node], end = rowend[node];
    for (int j = beg; j < end; j += 64) {
        int m = end - j; if (m > 64) m = 64;
        int   c = 0; float ww = 0.0f;
        if (lane < m) { c = col[j + lane]; ww = wv[j + lane]; }
        for (int t = 0; t < m; ++t) {
            int   s  = __shfl(c, t, 64);
            float wj = __shfl(ww, t, 64);
            if (lane < D) acc += wj * xin[s * D + lane];
        }
    }

    float d = (lane < D) ? (acc - f) : 0.0f;
    float ssum = d * d;
    #pragma unroll
    for (int m2 = 1; m2 < 64; m2 <<= 1) ssum += __shfl_xor(ssum, m2, 64);
    float norm = sqrtf(ssum);
    float scale = (norm > 0.0f) ? fmaxf(norm - GLAM, 0.0f) / norm : 0.0f;
    if (lane < D) xout[node * D + lane] = f + scale * d;
}

extern "C" void kernel_launch(void* const* d_in, const int* in_sizes, int n_in,
                              void* d_out, int out_size, void* d_ws, size_t ws_size,
                              hipStream_t stream) {
    const float* feat = (const float*)d_in[0];
    const float* ew   = (const float*)d_in[1];
    const int* src = (const int*)d_in[2];
    const int* dst = (const int*)d_in[3];

    const int nd = in_sizes[0];      // N * D
    const int n  = nd / D;           // N nodes
    const int e  = in_sizes[1];      // E edges

    // workspace layout
    float* bufA   = (float*)d_ws;            // nd
    float* bufB   = bufA + nd;               // nd
    float* odeg   = bufB + nd;               // n  -> inv_sqrt_out
    float* ideg   = odeg + n;                // n  -> inv_sqrt_in
    int*   cnt    = (int*)(ideg + n);        // n
    int*   rowptr = cnt + n;                 // n
    int*   cursor = rowptr + n;              // n  (after scatter: row end)
    int*   bsum   = cursor + n;              // 128
    int*   col    = bsum + 128;              // e
    float* wv     = (float*)(col + e);       // e
    float* out    = (float*)d_out;

    const int B = 256;
    const int gN  = (n + B - 1) / B;
    const int gE  = (e + B - 1) / B;
    const int NB  = (n + SCAN_B - 1) / SCAN_B;   // scan blocks (98 for n=100k)

    k_init<<<gN, B, 0, stream>>>(odeg, ideg, cnt, n);
    k_deg_hist<<<gE, B, 0, stream>>>(ew, src, dst, odeg, ideg, cnt, e);
    k_rsqrt<<<gN, B, 0, stream>>>(odeg, ideg, n);
    k_scan1<<<NB, SCAN_B, 0, stream>>>(cnt, rowptr, bsum, n);
    k_scan2<<<1, SCAN_B, 0, stream>>>(bsum, NB);
    k_scan3<<<NB, SCAN_B, 0, stream>>>(rowptr, cursor, bsum, n);
    k_scatter<<<gE, B, 0, stream>>>(ew, src, dst, odeg, ideg, cursor, col, wv, e);

    const int wavesPerBlock = B / 64;            // 4
    const int iterGrid = (n + wavesPerBlock - 1) / wavesPerBlock;

    // iter1: feat -> bufA ; iter2: bufA -> bufB ; iter3: bufB -> d_out
    k_iter<<<iterGrid, B, 0, stream>>>(rowptr, cursor, col, wv, feat, feat, odeg, ideg, bufA, n);
    k_iter<<<iterGrid, B, 0, stream>>>(rowptr, cursor, col, wv, bufA, feat, odeg, ideg, bufB, n);
    k_iter<<<iterGrid, B, 0, stream>>>(rowptr, cursor, col, wv, bufB, feat, odeg, ideg, out, n);
}

// Round 4
// 533.197 us; speedup vs baseline: 2.5559x; 1.4393x over previous
//
#include <hip/hip_runtime.h>
#include <hip/hip_bf16.h>

#define D 50
#define GLAM 0.05555555555555555f   // gamma * lambda = (1/(2*0.9)) * 0.1
#define SCAN_B 1024
#define MASK44 ((1ULL << 44) - 1)
#define FIXS 16777216.0f            // 2^24 fixed-point scale
#define INV_FIXS (1.0f / 16777216.0f)

typedef unsigned long long u64;

// ---- init: packed (cnt=0, ideg=1.0 fixed) for self loop; odeg = 1.0 ----
__global__ void k_init(u64* __restrict__ pkdeg, float* __restrict__ odeg, int n) {
    int i = blockIdx.x * blockDim.x + threadIdx.x;
    if (i < n) { pkdeg[i] = (u64)(1 << 24); odeg[i] = 1.0f; }
}

// ---- weighted degrees + dst histogram: 2 atomics per edge ----
__global__ void k_deg_hist(const float* __restrict__ ew, const int* __restrict__ src,
                           const int* __restrict__ dst, u64* __restrict__ pkdeg,
                           float* __restrict__ odeg, int e) {
    int i = blockIdx.x * blockDim.x + threadIdx.x;
    if (i < e) {
        float w = ew[i];
        int s = src[i], t = dst[i];
        u64 pk = (1ULL << 44) + (u64)(w * FIXS + 0.5f);
        atomicAdd(&pkdeg[t], pk);
        atomicAdd(&odeg[s], w);
    }
}

// ---- unpack: cnt, isi = rsqrt(ideg); iso = rsqrt(odeg) in place ----
__global__ void k_post(const u64* __restrict__ pkdeg, float* __restrict__ odeg,
                       float* __restrict__ isi, int* __restrict__ cnt, int n) {
    int i = blockIdx.x * blockDim.x + threadIdx.x;
    if (i < n) {
        u64 p = pkdeg[i];
        cnt[i] = (int)(p >> 44);
        isi[i] = rsqrtf((float)(p & MASK44) * INV_FIXS);
        odeg[i] = rsqrtf(odeg[i]);   // becomes iso
    }
}

// ---- exclusive scan of cnt -> rowptr (3-kernel standard scan) ----
__global__ void k_scan1(const int* __restrict__ cnt, int* __restrict__ rowptr,
                        int* __restrict__ bsum, int n) {
    __shared__ int s[SCAN_B];
    int i = blockIdx.x * SCAN_B + threadIdx.x;
    int v = (i < n) ? cnt[i] : 0;
    s[threadIdx.x] = v; __syncthreads();
    for (int off = 1; off < SCAN_B; off <<= 1) {
        int t = (threadIdx.x >= (unsigned)off) ? s[threadIdx.x - off] : 0;
        __syncthreads();
        s[threadIdx.x] += t; __syncthreads();
    }
    if (i < n) rowptr[i] = s[threadIdx.x] - v;          // exclusive
    if (threadIdx.x == SCAN_B - 1) bsum[blockIdx.x] = s[threadIdx.x];
}

__global__ void k_scan2(int* __restrict__ bsum, int nb) {
    __shared__ int s[SCAN_B];
    int v = (threadIdx.x < (unsigned)nb) ? bsum[threadIdx.x] : 0;
    s[threadIdx.x] = v; __syncthreads();
    for (int off = 1; off < SCAN_B; off <<= 1) {
        int t = (threadIdx.x >= (unsigned)off) ? s[threadIdx.x - off] : 0;
        __syncthreads();
        s[threadIdx.x] += t; __syncthreads();
    }
    if (threadIdx.x < (unsigned)nb) bsum[threadIdx.x] = s[threadIdx.x] - v;  // exclusive
}

__global__ void k_scan3(int* __restrict__ rowptr, int* __restrict__ cursor,
                        const int* __restrict__ bsum, int n) {
    int i = blockIdx.x * SCAN_B + threadIdx.x;
    if (i < n) {
        int r = rowptr[i] + bsum[blockIdx.x];
        rowptr[i] = r;
        cursor[i] = r;
    }
}

// ---- scatter edges into dst-CSR: packed (col | wv) single 8B store ----
__global__ void k_scatter(const float* __restrict__ ew, const int* __restrict__ src,
                          const int* __restrict__ dst, const float* __restrict__ iso,
                          const float* __restrict__ isi, int* __restrict__ cursor,
                          u64* __restrict__ pe, int e) {
    int i = blockIdx.x * blockDim.x + threadIdx.x;
    if (i < e) {
        int s = src[i], t = dst[i];
        int pos = atomicAdd(&cursor[t], 1);
        float wv = ew[i] * iso[s] * isi[t];
        pe[pos] = (u64)(unsigned)s | ((u64)__float_as_uint(wv) << 32);
    }
}

// ---- fused iteration: self-loop + CSR gather (4-way ILP) + prox ----
__global__ void k_iter(const int* __restrict__ rowptr, const int* __restrict__ rowend,
                       const u64* __restrict__ pe,
                       const float* __restrict__ xin, const float* __restrict__ feat,
                       const float* __restrict__ iso, const float* __restrict__ isi,
                       float* __restrict__ xout, int n) {
    int lane = threadIdx.x & 63;
    int node = blockIdx.x * (blockDim.x >> 6) + (threadIdx.x >> 6);
    if (node >= n) return;

    float selfw = iso[node] * isi[node];
    float f = 0.0f, acc = 0.0f;
    if (lane < D) {
        f = feat[node * D + lane];
        acc = selfw * xin[node * D + lane];
    }

    int beg = rowptr[node], end = rowend[node];
    for (int j = beg; j < end; j += 64) {
        int m = end - j; if (m > 64) m = 64;
        int c = 0; float ww = 0.0f;
        if (lane < m) {
            u64 p = pe[j + lane];
            c = (int)(unsigned)(p & 0xffffffffULL);
            ww = __uint_as_float((unsigned)(p >> 32));
        }
        int t = 0;
        for (; t + 4 <= m; t += 4) {
            int s0 = __shfl(c, t, 64),     s1 = __shfl(c, t + 1, 64);
            int s2 = __shfl(c, t + 2, 64), s3 = __shfl(c, t + 3, 64);
            float w0 = __shfl(ww, t, 64),     w1 = __shfl(ww, t + 1, 64);
            float w2 = __shfl(ww, t + 2, 64), w3 = __shfl(ww, t + 3, 64);
            if (lane < D) {
                float x0 = xin[s0 * D + lane];
                float x1 = xin[s1 * D + lane];
                float x2 = xin[s2 * D + lane];
                float x3 = xin[s3 * D + lane];
                acc += w0 * x0; acc += w1 * x1; acc += w2 * x2; acc += w3 * x3;
            }
        }
        for (; t < m; ++t) {
            int   s  = __shfl(c, t, 64);
            float wj = __shfl(ww, t, 64);
            if (lane < D) acc += wj * xin[s * D + lane];
        }
    }

    float d = (lane < D) ? (acc - f) : 0.0f;
    float ssum = d * d;
    #pragma unroll
    for (int m2 = 1; m2 < 64; m2 <<= 1) ssum += __shfl_xor(ssum, m2, 64);
    float norm = sqrtf(ssum);
    float scale = (norm > 0.0f) ? fmaxf(norm - GLAM, 0.0f) / norm : 0.0f;
    if (lane < D) xout[node * D + lane] = f + scale * d;
}

extern "C" void kernel_launch(void* const* d_in, const int* in_sizes, int n_in,
                              void* d_out, int out_size, void* d_ws, size_t ws_size,
                              hipStream_t stream) {
    const float* feat = (const float*)d_in[0];
    const float* ew   = (const float*)d_in[1];
    const int* src = (const int*)d_in[2];
    const int* dst = (const int*)d_in[3];

    const int nd = in_sizes[0];      // N * D
    const int n  = nd / D;           // N nodes
    const int e  = in_sizes[1];      // E edges

    // workspace layout (8B-aligned arrays first)
    u64*   pkdeg  = (u64*)d_ws;              // n
    u64*   pe     = pkdeg + n;               // e  (packed col|wv)
    float* bufA   = (float*)(pe + e);        // nd
    float* bufB   = bufA + nd;               // nd
    float* odeg   = bufB + nd;               // n  -> iso after k_post
    float* isi    = odeg + n;                // n
    int*   cnt    = (int*)(isi + n);         // n
    int*   rowptr = cnt + n;                 // n
    int*   cursor = rowptr + n;              // n  (after scatter: row end)
    int*   bsum   = cursor + n;              // 128
    float* out    = (float*)d_out;

    const int B = 256;
    const int gN = (n + B - 1) / B;
    const int gE = (e + B - 1) / B;
    const int NB = (n + SCAN_B - 1) / SCAN_B;

    k_init<<<gN, B, 0, stream>>>(pkdeg, odeg, n);
    k_deg_hist<<<gE, B, 0, stream>>>(ew, src, dst, pkdeg, odeg, e);
    k_post<<<gN, B, 0, stream>>>(pkdeg, odeg, isi, cnt, n);
    k_scan1<<<NB, SCAN_B, 0, stream>>>(cnt, rowptr, bsum, n);
    k_scan2<<<1, SCAN_B, 0, stream>>>(bsum, NB);
    k_scan3<<<NB, SCAN_B, 0, stream>>>(rowptr, cursor, bsum, n);
    k_scatter<<<gE, B, 0, stream>>>(ew, src, dst, odeg, isi, cursor, pe, e);

    const int wavesPerBlock = B / 64;            // 4
    const int iterGrid = (n + wavesPerBlock - 1) / wavesPerBlock;

    // iter1: feat -> bufA ; iter2: bufA -> bufB ; iter3: bufB -> d_out
    k_iter<<<iterGrid, B, 0, stream>>>(rowptr, cursor, pe, feat, feat, odeg, isi, bufA, n);
    k_iter<<<iterGrid, B, 0, stream>>>(rowptr, cursor, pe, bufA, feat, odeg, isi, bufB, n);
    k_iter<<<iterGrid, B, 0, stream>>>(rowptr, cursor, pe, bufB, feat, odeg, isi, out, n);
}

// Round 5
// 505.329 us; speedup vs baseline: 2.6969x; 1.0551x over previous
//
#include <hip/hip_runtime.h>
#include <hip/hip_bf16.h>

#define D 50
#define GLAM 0.05555555555555555f   // gamma * lambda = (1/(2*0.9)) * 0.1
#define SCAN_B 1024
#define MASK44 ((1ULL << 44) - 1)
#define FIXS 16777216.0f            // 2^24 fixed-point scale
#define INV_FIXS (1.0f / 16777216.0f)

typedef unsigned long long u64;

// ---- init: packed (cnt=0, ideg=1.0 fixed) for self loop; odeg = 1.0 ----
__global__ void k_init(u64* __restrict__ pkdeg, float* __restrict__ odeg, int n) {
    int i = blockIdx.x * blockDim.x + threadIdx.x;
    if (i < n) { pkdeg[i] = (u64)(1 << 24); odeg[i] = 1.0f; }
}

// ---- weighted degrees + dst histogram; atomic RETURN gives edge rank ----
__global__ void k_deg_hist(const float* __restrict__ ew, const int* __restrict__ src,
                           const int* __restrict__ dst, u64* __restrict__ pkdeg,
                           float* __restrict__ odeg, int* __restrict__ rank, int e) {
    int i = blockIdx.x * blockDim.x + threadIdx.x;
    if (i < e) {
        float w = ew[i];
        int s = src[i], t = dst[i];
        u64 pk = (1ULL << 44) + (u64)(w * FIXS + 0.5f);
        u64 old = atomicAdd(&pkdeg[t], pk);
        rank[i] = (int)(old >> 44);          // position within dst bucket
        atomicAdd(&odeg[s], w);
    }
}

// ---- unpack: cnt, isi = rsqrt(ideg); iso = rsqrt(odeg) in place ----
__global__ void k_post(const u64* __restrict__ pkdeg, float* __restrict__ odeg,
                       float* __restrict__ isi, int* __restrict__ cnt, int n) {
    int i = blockIdx.x * blockDim.x + threadIdx.x;
    if (i < n) {
        u64 p = pkdeg[i];
        cnt[i] = (int)(p >> 44);
        isi[i] = rsqrtf((float)(p & MASK44) * INV_FIXS);
        odeg[i] = rsqrtf(odeg[i]);   // becomes iso
    }
}

// ---- exclusive scan of cnt -> rowptr (3-kernel standard scan) ----
__global__ void k_scan1(const int* __restrict__ cnt, int* __restrict__ rowptr,
                        int* __restrict__ bsum, int n) {
    __shared__ int s[SCAN_B];
    int i = blockIdx.x * SCAN_B + threadIdx.x;
    int v = (i < n) ? cnt[i] : 0;
    s[threadIdx.x] = v; __syncthreads();
    for (int off = 1; off < SCAN_B; off <<= 1) {
        int t = (threadIdx.x >= (unsigned)off) ? s[threadIdx.x - off] : 0;
        __syncthreads();
        s[threadIdx.x] += t; __syncthreads();
    }
    if (i < n) rowptr[i] = s[threadIdx.x] - v;          // exclusive
    if (threadIdx.x == SCAN_B - 1) bsum[blockIdx.x] = s[threadIdx.x];
}

__global__ void k_scan2(int* __restrict__ bsum, int nb) {
    __shared__ int s[SCAN_B];
    int v = (threadIdx.x < (unsigned)nb) ? bsum[threadIdx.x] : 0;
    s[threadIdx.x] = v; __syncthreads();
    for (int off = 1; off < SCAN_B; off <<= 1) {
        int t = (threadIdx.x >= (unsigned)off) ? s[threadIdx.x - off] : 0;
        __syncthreads();
        s[threadIdx.x] += t; __syncthreads();
    }
    if (threadIdx.x < (unsigned)nb) bsum[threadIdx.x] = s[threadIdx.x] - v;  // exclusive
}

__global__ void k_scan3(int* __restrict__ rowptr, const int* __restrict__ bsum, int n) {
    int i = blockIdx.x * SCAN_B + threadIdx.x;
    if (i < n) rowptr[i] += bsum[blockIdx.x];
}

// ---- scatter edges into dst-CSR: NO atomics (rank from histogram) ----
__global__ void k_scatter(const float* __restrict__ ew, const int* __restrict__ src,
                          const int* __restrict__ dst, const float* __restrict__ iso,
                          const float* __restrict__ isi, const int* __restrict__ rowptr,
                          const int* __restrict__ rank, u64* __restrict__ pe, int e) {
    int i = blockIdx.x * blockDim.x + threadIdx.x;
    if (i < e) {
        int s = src[i], t = dst[i];
        int pos = rowptr[t] + rank[i];
        float wv = ew[i] * iso[s] * isi[t];
        pe[pos] = (u64)(unsigned)s | ((u64)__float_as_uint(wv) << 32);
    }
}

// ---- fused iteration: self-loop + CSR gather (4-way ILP) + prox ----
__global__ void k_iter(const int* __restrict__ rowptr, const int* __restrict__ cnt,
                       const u64* __restrict__ pe,
                       const float* __restrict__ xin, const float* __restrict__ feat,
                       const float* __restrict__ iso, const float* __restrict__ isi,
                       float* __restrict__ xout, int n) {
    int lane = threadIdx.x & 63;
    int node = blockIdx.x * (blockDim.x >> 6) + (threadIdx.x >> 6);
    if (node >= n) return;

    float selfw = iso[node] * isi[node];
    float f = 0.0f, acc = 0.0f;
    if (lane < D) {
        f = feat[node * D + lane];
        acc = selfw * xin[node * D + lane];
    }

    int beg = rowptr[node], end = beg + cnt[node];
    for (int j = beg; j < end; j += 64) {
        int m = end - j; if (m > 64) m = 64;
        int c = 0; float ww = 0.0f;
        if (lane < m) {
            u64 p = pe[j + lane];
            c = (int)(unsigned)(p & 0xffffffffULL);
            ww = __uint_as_float((unsigned)(p >> 32));
        }
        int t = 0;
        for (; t + 4 <= m; t += 4) {
            int s0 = __shfl(c, t, 64),     s1 = __shfl(c, t + 1, 64);
            int s2 = __shfl(c, t + 2, 64), s3 = __shfl(c, t + 3, 64);
            float w0 = __shfl(ww, t, 64),     w1 = __shfl(ww, t + 1, 64);
            float w2 = __shfl(ww, t + 2, 64), w3 = __shfl(ww, t + 3, 64);
            if (lane < D) {
                float x0 = xin[s0 * D + lane];
                float x1 = xin[s1 * D + lane];
                float x2 = xin[s2 * D + lane];
                float x3 = xin[s3 * D + lane];
                acc += w0 * x0; acc += w1 * x1; acc += w2 * x2; acc += w3 * x3;
            }
        }
        for (; t < m; ++t) {
            int   s  = __shfl(c, t, 64);
            float wj = __shfl(ww, t, 64);
            if (lane < D) acc += wj * xin[s * D + lane];
        }
    }

    float d = (lane < D) ? (acc - f) : 0.0f;
    float ssum = d * d;
    #pragma unroll
    for (int m2 = 1; m2 < 64; m2 <<= 1) ssum += __shfl_xor(ssum, m2, 64);
    float norm = sqrtf(ssum);
    float scale = (norm > 0.0f) ? fmaxf(norm - GLAM, 0.0f) / norm : 0.0f;
    if (lane < D) xout[node * D + lane] = f + scale * d;
}

extern "C" void kernel_launch(void* const* d_in, const int* in_sizes, int n_in,
                              void* d_out, int out_size, void* d_ws, size_t ws_size,
                              hipStream_t stream) {
    const float* feat = (const float*)d_in[0];
    const float* ew   = (const float*)d_in[1];
    const int* src = (const int*)d_in[2];
    const int* dst = (const int*)d_in[3];

    const int nd = in_sizes[0];      // N * D
    const int n  = nd / D;           // N nodes
    const int e  = in_sizes[1];      // E edges

    // workspace layout (8B-aligned arrays first)
    u64*   pkdeg  = (u64*)d_ws;              // n
    u64*   pe     = pkdeg + n;               // e  (packed col|wv)
    float* bufA   = (float*)(pe + e);        // nd
    float* bufB   = bufA + nd;               // nd
    float* odeg   = bufB + nd;               // n  -> iso after k_post
    float* isi    = odeg + n;                // n
    int*   cnt    = (int*)(isi + n);         // n
    int*   rowptr = cnt + n;                 // n
    int*   rank   = rowptr + n;              // e
    int*   bsum   = rank + e;                // 128
    float* out    = (float*)d_out;

    const int B = 256;
    const int gN = (n + B - 1) / B;
    const int gE = (e + B - 1) / B;
    const int NB = (n + SCAN_B - 1) / SCAN_B;

    k_init<<<gN, B, 0, stream>>>(pkdeg, odeg, n);
    k_deg_hist<<<gE, B, 0, stream>>>(ew, src, dst, pkdeg, odeg, rank, e);
    k_post<<<gN, B, 0, stream>>>(pkdeg, odeg, isi, cnt, n);
    k_scan1<<<NB, SCAN_B, 0, stream>>>(cnt, rowptr, bsum, n);
    k_scan2<<<1, SCAN_B, 0, stream>>>(bsum, NB);
    k_scan3<<<NB, SCAN_B, 0, stream>>>(rowptr, bsum, n);
    k_scatter<<<gE, B, 0, stream>>>(ew, src, dst, odeg, isi, rowptr, rank, pe, e);

    const int wavesPerBlock = B / 64;            // 4
    const int iterGrid = (n + wavesPerBlock - 1) / wavesPerBlock;

    // iter1: feat -> bufA ; iter2: bufA -> bufB ; iter3: bufB -> d_out
    k_iter<<<iterGrid, B, 0, stream>>>(rowptr, cnt, pe, feat, feat, odeg, isi, bufA, n);
    k_iter<<<iterGrid, B, 0, stream>>>(rowptr, cnt, pe, bufA, feat, odeg, isi, bufB, n);
    k_iter<<<iterGrid, B, 0, stream>>>(rowptr, cnt, pe, bufB, feat, odeg, isi, out, n);
}